// Round 24
// baseline (939.264 us; speedup 1.0000x reference)
//
#include <hip/hip_runtime.h>
#include <math.h>

#define TT 256
#define HH 100
#define GG 400
#define BB 512

typedef float  f32x4  __attribute__((ext_vector_type(4)));
typedef short  bf16x8 __attribute__((ext_vector_type(8)));

// ---- DPP quad-perm helpers (C++ recur for layer 0) -------------------------
#define DPP_ROT1 147
#define DPP_ROT2 78
#define DPP_ROT3 57
#define DPP_XOR1 177
#define DPP_XOR2 78
#define DPP_XOR3 27

template<int CTRL>
__device__ __forceinline__ float dppf(float v) {
    int i = __float_as_int(v);
    int r = __builtin_amdgcn_update_dpp(i, i, CTRL, 0xf, 0xf, false);
    return __int_as_float(r);
}

__device__ __forceinline__ float fexp2(float x) {
    float r; asm("v_exp_f32 %0, %1" : "=v"(r) : "v"(x)); return r;
}
__device__ __forceinline__ float frcp(float x) {
    float r; asm("v_rcp_f32 %0, %1" : "=v"(r) : "v"(x)); return r;
}
#define LOG2E 1.44269504088896f

__device__ __forceinline__ unsigned bf16rne(float x) {
    unsigned b = __float_as_uint(x);
    return (b + 0x7FFFu + ((b >> 16) & 1u)) >> 16;
}

__device__ __forceinline__ void bar_lds() {
    asm volatile("s_waitcnt lgkmcnt(0)" ::: "memory");
    __builtin_amdgcn_s_barrier();
    asm volatile("" ::: "memory");
}

// ======================= layer-0 recurrence (C++, R19) =======================
template<int LK>
__global__ void __launch_bounds__(448, 2)
lstm_recur(const float* __restrict__ x, const float* __restrict__ pre,
           const float* __restrict__ Whh, const float* __restrict__ Wih0,
           const float* __restrict__ bih, const float* __restrict__ bhh,
           const float* __restrict__ head_w, const float* __restrict__ head_b,
           float* __restrict__ hs, float* __restrict__ out)
{
    __shared__ float hbuf[2][4][28];

    const int tid = threadIdx.x;
    const int b   = blockIdx.x;
    const int u   = tid >> 2, ty = tid & 3;
    const int g   = ty * HH + u;
    const bool on = (tid < GG);

    float Wq[4][25];
    float w0a = 0.f, w0b = 0.f, bias = 0.f;
    if (on) {
        #pragma unroll
        for (int d = 0; d < 4; ++d) {
            const float* wrow = Whh + (((ty + d) & 3) * HH + u) * HH + 25 * ty;
            #pragma unroll
            for (int k = 0; k < 25; ++k) Wq[d][k] = wrow[k];
        }
        if (LK == 0) {
            w0a = Wih0[2 * g]; w0b = Wih0[2 * g + 1];
            bias = bih[g] + bhh[g];
        }
    }
    if (tid < 224) (&hbuf[0][0][0])[tid] = 0.f;
    float c = 0.f;
    const int q_w = u / 25, i_w = u % 25;
    __syncthreads();

    float p0 = 0.f;
    float2 xa = {0.f, 0.f};
    if (on) {
        if (LK == 0) xa = *(const float2*)(x + (size_t)b * TT * 2);
        else         p0 = pre[((size_t)0 * BB + b) * GG + g];
    }

    for (int t = 0; t < TT; ++t) {
        const int cur = t & 1, nxt = cur ^ 1;
        if (on) {
            float ext;
            if (LK == 0) ext = bias + w0a * xa.x + w0b * xa.y;
            else         ext = p0;

            const int tn = (t + 1 < TT) ? t + 1 : t;
            if (LK == 0) xa = *(const float2*)(x + ((size_t)b * TT + tn) * 2);
            else         p0 = pre[((size_t)tn * BB + b) * GG + g];

            const float4* hq = (const float4*)&hbuf[cur][ty][0];

            float pA = 0.f, pB = 0.f, pC = 0.f, pD = 0.f;
            #pragma unroll
            for (int i = 0; i < 6; ++i) {
                const float4 h4 = hq[i];
                pA += Wq[0][4*i+0] * h4.x; pB += Wq[1][4*i+0] * h4.x;
                pC += Wq[2][4*i+0] * h4.x; pD += Wq[3][4*i+0] * h4.x;
                pA += Wq[0][4*i+1] * h4.y; pB += Wq[1][4*i+1] * h4.y;
                pC += Wq[2][4*i+1] * h4.y; pD += Wq[3][4*i+1] * h4.y;
                pA += Wq[0][4*i+2] * h4.z; pB += Wq[1][4*i+2] * h4.z;
                pC += Wq[2][4*i+2] * h4.z; pD += Wq[3][4*i+2] * h4.z;
                pA += Wq[0][4*i+3] * h4.w; pB += Wq[1][4*i+3] * h4.w;
                pC += Wq[2][4*i+3] * h4.w; pD += Wq[3][4*i+3] * h4.w;
            }
            const float hl = hq[6].x;
            pA += Wq[0][24] * hl; pB += Wq[1][24] * hl;
            pC += Wq[2][24] * hl; pD += Wq[3][24] * hl;

            float tot = pA + dppf<DPP_ROT1>(pB) + dppf<DPP_ROT2>(pC)
                           + dppf<DPP_ROT3>(pD) + ext;

            const bool isG = (ty == 2);
            float v = isG ? 2.f * tot : tot;
            float s = frcp(1.f + fexp2(-LOG2E * v));
            if (isG) s = 2.f * s - 1.f;

            float B0 = dppf<DPP_XOR1>(s), C0 = dppf<DPP_XOR2>(s), D0 = dppf<DPP_XOR3>(s);

            if (ty == 0) {
                c = B0 * c + s * C0;
                float th = 2.f * frcp(1.f + fexp2(-2.f * LOG2E * c)) - 1.f;
                float hv = D0 * th;
                hbuf[nxt][q_w][i_w] = hv;
                if (LK < 2) hs[((size_t)b * TT + t) * HH + u] = hv;
            }
        }
        bar_lds();
    }

    if (LK == 2 && tid < 64) {
        const int lane = tid;
        float p = hbuf[0][lane / 25][lane % 25] * head_w[lane];
        if (lane < 36) {
            const int k2 = 64 + lane;
            p += hbuf[0][k2 / 25][k2 % 25] * head_w[k2];
        }
        #pragma unroll
        for (int off = 32; off; off >>= 1) p += __shfl_down(p, off);
        if (lane == 0) out[b] = p + head_b[0];
    }
}

// ============ layers 1/2 recurrence (k-eighth asm, 16 waves/CU) ==============
// R23 lesson: 100-W-reg asm forces VGPR alloc 256 -> 8 waves -> 1x7-wave block
// per CU (no barrier interleave) -> slower than C++. R24: k-EIGHTH split:
// Wq[4][13]=52 regs, whole kernel <=128 VGPR -> 16 waves/CU.
// 256 blocks x 1024 threads, 2 rows/block. Thread (u=tid>>3, ty=(tid>>1)&3,
// kh=tid&1, seg s=tid&7): slot d = gate (ty^d)*100+u over k in [13s,13s+13).
// Combine: kh-sum x1; gate-sum tot(ty) = pA + x2(pB) + x4(pC) + x6(pD)
// (lane l^2 has ty^1, its slot1 = (ty^1)^1 = ty; similarly x4/x6).
// BitMode swizzles 0x041F/0x081F/0x101F/0x181F (verified family, R22/R23).
// W tail k>=100 (s==7): exec-masked loads + prezeroed regs; h LDS pads zero.
// h LDS flat [buf][row][128]f; buf stride 0x400 (XOR toggle), align 2048.
#define FME(wa,wb,wc,wd,h0,h1) \
    "v_fmac_f32 v44, v" #wa ", v" #h0 "\n\t" \
    "v_fmac_f32 v45, v" #wb ", v" #h0 "\n\t" \
    "v_fmac_f32 v46, v" #wc ", v" #h0 "\n\t" \
    "v_fmac_f32 v47, v" #wd ", v" #h0 "\n\t" \
    "v_fmac_f32 v48, v" #wa ", v" #h1 "\n\t" \
    "v_fmac_f32 v49, v" #wb ", v" #h1 "\n\t" \
    "v_fmac_f32 v50, v" #wc ", v" #h1 "\n\t" \
    "v_fmac_f32 v51, v" #wd ", v" #h1 "\n\t"

__global__ void __launch_bounds__(1024, 1)
lstm_recur_asm(const float* __restrict__ pre,   // [T*B][400] bias folded
               const float* __restrict__ Whh,   // [400][100] this layer
               const float* __restrict__ head_w,
               const float* __restrict__ head_b,
               float* __restrict__ hs,          // [B][T][100] out
               float* __restrict__ out,         // [B] (head)
               int do_head)
{
    __shared__ __align__(2048) float hbuf[2][256];  // [buf][row*128 + u]

    const int tid = threadIdx.x;
    const int b0  = blockIdx.x * 2;
    const int u   = tid >> 3;
    const int s   = tid & 7;
    const int ty  = s >> 1;
    const int uc  = (u < 100) ? u : 99;
    const int g   = ty * HH + uc;
    const bool on = (u < 100);

    const unsigned long long onm = __ballot(on);
    const unsigned long long m7  = onm & ~__ballot(s == 7);   // exec for W tail
    const unsigned long long wrm = __ballot(on && s == 0);    // writer lanes

    // W slot byte offsets: gate (ty^d)*100+uc, k start 13s
    unsigned wo0 = (unsigned)((((ty ^ 0)) * 100 + uc) * 400 + s * 52);
    unsigned wo1 = (unsigned)((((ty ^ 1)) * 100 + uc) * 400 + s * 52);
    unsigned wo2 = (unsigned)((((ty ^ 2)) * 100 + uc) * 400 + s * 52);
    unsigned wo3 = (unsigned)((((ty ^ 3)) * 100 + uc) * 400 + s * 52);
    unsigned pv0  = (unsigned)((b0    ) * 1600 + g * 4);
    unsigned pv1  = (unsigned)((b0 + 1) * 1600 + g * 4);
    unsigned pvm0 = pv0 + 255u * 819200u;
    unsigned pvm1 = pv1 + 255u * 819200u;
    unsigned hs0  = (unsigned)(b0 * 102400 + uc * 4);
    unsigned hrb  = (unsigned)(s * 52);            // read base, buf0 (row1 = +512)
    unsigned hwb  = 0x400u + (unsigned)(uc * 4);   // write base, buf1 (row1 = +512)
    float mg = (ty == 2) ? -2.8853900818f : -1.4426950409f;
    float pk = (ty == 2) ? 2.f : 1.f;
    float qk = (ty == 2) ? -1.f : 0.f;

    if (tid < 512) (&hbuf[0][0])[tid] = 0.f;   // zero both buffers (pads stay 0)
    __syncthreads();

    asm volatile(
        // ---- preamble ----
        "s_mov_b64 s[34:35], exec\n\t"
        "s_mov_b64 exec, %[onm]\n\t"
        "v_mov_b32 v2, %[wo0]\n\t"
        "v_mov_b32 v3, %[wo1]\n\t"
        "v_mov_b32 v4, %[wo2]\n\t"
        "v_mov_b32 v5, %[wo3]\n\t"
        "v_mov_b32 v6, %[pv0]\n\t"
        "v_mov_b32 v7, %[pv1]\n\t"
        "v_mov_b32 v8, %[hrb]\n\t"
        "v_mov_b32 v9, %[hwb]\n\t"
        "v_mov_b32 v10, %[hs0]\n\t"
        "v_add_u32 v11, 0x19000, v10\n\t"   // hs row1 (+102400 B)
        "v_mov_b32 v61, 0\n\t"              // c0
        "v_mov_b32 v62, 0\n\t"              // c1
        // pre-zero W tail regs (s==7 lanes keep zeros)
        "v_mov_b32 v73, 0\n\t"  "v_mov_b32 v74, 0\n\t"
        "v_mov_b32 v75, 0\n\t"  "v_mov_b32 v76, 0\n\t"
        "v_mov_b32 v86, 0\n\t"  "v_mov_b32 v87, 0\n\t"
        "v_mov_b32 v88, 0\n\t"  "v_mov_b32 v89, 0\n\t"
        "v_mov_b32 v99, 0\n\t"  "v_mov_b32 v100, 0\n\t"
        "v_mov_b32 v101, 0\n\t" "v_mov_b32 v102, 0\n\t"
        "v_mov_b32 v112, 0\n\t" "v_mov_b32 v113, 0\n\t"
        "v_mov_b32 v114, 0\n\t" "v_mov_b32 v115, 0\n\t"
        // W head loads (k idx 0..8), all active lanes
        "global_load_dword v64, v2, %[whh]\n\t"
        "global_load_dword v65, v2, %[whh] offset:4\n\t"
        "global_load_dword v66, v2, %[whh] offset:8\n\t"
        "global_load_dword v67, v2, %[whh] offset:12\n\t"
        "global_load_dword v68, v2, %[whh] offset:16\n\t"
        "global_load_dword v69, v2, %[whh] offset:20\n\t"
        "global_load_dword v70, v2, %[whh] offset:24\n\t"
        "global_load_dword v71, v2, %[whh] offset:28\n\t"
        "global_load_dword v72, v2, %[whh] offset:32\n\t"
        "global_load_dword v77, v3, %[whh]\n\t"
        "global_load_dword v78, v3, %[whh] offset:4\n\t"
        "global_load_dword v79, v3, %[whh] offset:8\n\t"
        "global_load_dword v80, v3, %[whh] offset:12\n\t"
        "global_load_dword v81, v3, %[whh] offset:16\n\t"
        "global_load_dword v82, v3, %[whh] offset:20\n\t"
        "global_load_dword v83, v3, %[whh] offset:24\n\t"
        "global_load_dword v84, v3, %[whh] offset:28\n\t"
        "global_load_dword v85, v3, %[whh] offset:32\n\t"
        "global_load_dword v90, v4, %[whh]\n\t"
        "global_load_dword v91, v4, %[whh] offset:4\n\t"
        "global_load_dword v92, v4, %[whh] offset:8\n\t"
        "global_load_dword v93, v4, %[whh] offset:12\n\t"
        "global_load_dword v94, v4, %[whh] offset:16\n\t"
        "global_load_dword v95, v4, %[whh] offset:20\n\t"
        "global_load_dword v96, v4, %[whh] offset:24\n\t"
        "global_load_dword v97, v4, %[whh] offset:28\n\t"
        "global_load_dword v98, v4, %[whh] offset:32\n\t"
        "global_load_dword v103, v5, %[whh]\n\t"
        "global_load_dword v104, v5, %[whh] offset:4\n\t"
        "global_load_dword v105, v5, %[whh] offset:8\n\t"
        "global_load_dword v106, v5, %[whh] offset:12\n\t"
        "global_load_dword v107, v5, %[whh] offset:16\n\t"
        "global_load_dword v108, v5, %[whh] offset:20\n\t"
        "global_load_dword v109, v5, %[whh] offset:24\n\t"
        "global_load_dword v110, v5, %[whh] offset:28\n\t"
        "global_load_dword v111, v5, %[whh] offset:32\n\t"
        // W tail loads (k idx 9..12) exclude s==7 lanes
        "s_mov_b64 exec, %[m7]\n\t"
        "global_load_dword v73, v2, %[whh] offset:36\n\t"
        "global_load_dword v74, v2, %[whh] offset:40\n\t"
        "global_load_dword v75, v2, %[whh] offset:44\n\t"
        "global_load_dword v76, v2, %[whh] offset:48\n\t"
        "global_load_dword v86, v3, %[whh] offset:36\n\t"
        "global_load_dword v87, v3, %[whh] offset:40\n\t"
        "global_load_dword v88, v3, %[whh] offset:44\n\t"
        "global_load_dword v89, v3, %[whh] offset:48\n\t"
        "global_load_dword v99, v4, %[whh] offset:36\n\t"
        "global_load_dword v100, v4, %[whh] offset:40\n\t"
        "global_load_dword v101, v4, %[whh] offset:44\n\t"
        "global_load_dword v102, v4, %[whh] offset:48\n\t"
        "global_load_dword v112, v5, %[whh] offset:36\n\t"
        "global_load_dword v113, v5, %[whh] offset:40\n\t"
        "global_load_dword v114, v5, %[whh] offset:44\n\t"
        "global_load_dword v115, v5, %[whh] offset:48\n\t"
        "s_mov_b64 exec, %[onm]\n\t"
        "global_load_dword v12, v6, %[pre]\n\t"     // p0(t=0)
        "global_load_dword v13, v7, %[pre]\n\t"     // p1(t=0)
        "s_movk_i32 s30, 0x100\n\t"
        "s_waitcnt vmcnt(0)\n\t"
        // ---- time loop ----
        "LT%=:\n\t"
        "s_waitcnt vmcnt(0)\n\t"
        "v_mov_b32 v14, v12\n\t"                    // ext0
        "v_mov_b32 v15, v13\n\t"                    // ext1
        "v_add_u32 v6, 0xC8000, v6\n\t"
        "v_min_u32 v6, v6, %[pvm0]\n\t"
        "v_add_u32 v7, 0xC8000, v7\n\t"
        "v_min_u32 v7, v7, %[pvm1]\n\t"
        "global_load_dword v12, v6, %[pre]\n\t"
        "global_load_dword v13, v7, %[pre]\n\t"
        // h reads: row0 -> v16-28, row1 -> v30-42 (dword offsets; row1 +128dw)
        "ds_read2_b32 v[16:17], v8 offset0:0 offset1:1\n\t"
        "ds_read2_b32 v[18:19], v8 offset0:2 offset1:3\n\t"
        "ds_read2_b32 v[20:21], v8 offset0:4 offset1:5\n\t"
        "ds_read2_b32 v[22:23], v8 offset0:6 offset1:7\n\t"
        "ds_read2_b32 v[24:25], v8 offset0:8 offset1:9\n\t"
        "ds_read2_b32 v[26:27], v8 offset0:10 offset1:11\n\t"
        "ds_read_b32 v28, v8 offset:48\n\t"
        "ds_read2_b32 v[30:31], v8 offset0:128 offset1:129\n\t"
        "ds_read2_b32 v[32:33], v8 offset0:130 offset1:131\n\t"
        "ds_read2_b32 v[34:35], v8 offset0:132 offset1:133\n\t"
        "ds_read2_b32 v[36:37], v8 offset0:134 offset1:135\n\t"
        "ds_read2_b32 v[38:39], v8 offset0:136 offset1:137\n\t"
        "ds_read2_b32 v[40:41], v8 offset0:138 offset1:139\n\t"
        "ds_read_b32 v42, v8 offset:560\n\t"
        "v_mov_b32 v44, 0\n\t" "v_mov_b32 v45, 0\n\t"
        "v_mov_b32 v46, 0\n\t" "v_mov_b32 v47, 0\n\t"
        "v_mov_b32 v48, 0\n\t" "v_mov_b32 v49, 0\n\t"
        "v_mov_b32 v50, 0\n\t" "v_mov_b32 v51, 0\n\t"
        "s_waitcnt lgkmcnt(0)\n\t"
        FME(64,77,90,103,16,30)   FME(65,78,91,104,17,31)
        FME(66,79,92,105,18,32)   FME(67,80,93,106,19,33)
        FME(68,81,94,107,20,34)   FME(69,82,95,108,21,35)
        FME(70,83,96,109,22,36)   FME(71,84,97,110,23,37)
        FME(72,85,98,111,24,38)   FME(73,86,99,112,25,39)
        FME(74,87,100,113,26,40)  FME(75,88,101,114,27,41)
        FME(76,89,102,115,28,42)
        // kh-sum: pX += x1(pX)
        "ds_swizzle_b32 v52, v44 offset:0x041F\n\t"
        "ds_swizzle_b32 v53, v45 offset:0x041F\n\t"
        "ds_swizzle_b32 v54, v46 offset:0x041F\n\t"
        "ds_swizzle_b32 v55, v47 offset:0x041F\n\t"
        "ds_swizzle_b32 v56, v48 offset:0x041F\n\t"
        "ds_swizzle_b32 v57, v49 offset:0x041F\n\t"
        "ds_swizzle_b32 v58, v50 offset:0x041F\n\t"
        "ds_swizzle_b32 v59, v51 offset:0x041F\n\t"
        "s_waitcnt lgkmcnt(0)\n\t"
        "v_add_f32 v44, v44, v52\n\t"
        "v_add_f32 v45, v45, v53\n\t"
        "v_add_f32 v46, v46, v54\n\t"
        "v_add_f32 v47, v47, v55\n\t"
        "v_add_f32 v48, v48, v56\n\t"
        "v_add_f32 v49, v49, v57\n\t"
        "v_add_f32 v50, v50, v58\n\t"
        "v_add_f32 v51, v51, v59\n\t"
        // gate-sum row0: tot0 = pA0 + x2(pB0) + x4(pC0) + x6(pD0) + ext0
        "ds_swizzle_b32 v52, v45 offset:0x081F\n\t"
        "ds_swizzle_b32 v53, v46 offset:0x101F\n\t"
        "ds_swizzle_b32 v54, v47 offset:0x181F\n\t"
        // gate-sum row1
        "ds_swizzle_b32 v56, v49 offset:0x081F\n\t"
        "ds_swizzle_b32 v57, v50 offset:0x101F\n\t"
        "ds_swizzle_b32 v58, v51 offset:0x181F\n\t"
        "s_waitcnt lgkmcnt(0)\n\t"
        "v_add_f32 v55, v44, v52\n\t"
        "v_add_f32 v55, v55, v53\n\t"
        "v_add_f32 v55, v55, v54\n\t"
        "v_add_f32 v55, v55, v14\n\t"               // tot0
        "v_add_f32 v59, v48, v56\n\t"
        "v_add_f32 v59, v59, v57\n\t"
        "v_add_f32 v59, v59, v58\n\t"
        "v_add_f32 v59, v59, v15\n\t"               // tot1
        // activations: s_r = pk*rcp(1+exp2(mg*tot_r)) + qk
        "v_mul_f32 v52, %[mg], v55\n\t"
        "v_exp_f32 v52, v52\n\t"
        "v_mul_f32 v53, %[mg], v59\n\t"
        "v_exp_f32 v53, v53\n\t"
        "s_nop 1\n\t"
        "v_add_f32 v52, 1.0, v52\n\t"
        "v_add_f32 v53, 1.0, v53\n\t"
        "v_rcp_f32 v52, v52\n\t"
        "v_rcp_f32 v53, v53\n\t"
        "s_nop 1\n\t"
        "v_fma_f32 v57, %[pk], v52, %[qk]\n\t"      // s0 (act)
        "v_fma_f32 v58, %[pk], v53, %[qk]\n\t"      // s1 (act)
        // gather gates to writer lanes: F=x2, G=x4, O=x6 (both rows)
        "ds_swizzle_b32 v52, v57 offset:0x081F\n\t"
        "ds_swizzle_b32 v53, v57 offset:0x101F\n\t"
        "ds_swizzle_b32 v54, v57 offset:0x181F\n\t"
        "ds_swizzle_b32 v44, v58 offset:0x081F\n\t"
        "ds_swizzle_b32 v45, v58 offset:0x101F\n\t"
        "ds_swizzle_b32 v46, v58 offset:0x181F\n\t"
        "s_waitcnt lgkmcnt(0)\n\t"
        // writer lanes (s==0): update c/h both rows
        "s_mov_b64 exec, %[wrm]\n\t"
        "v_mul_f32 v61, v52, v61\n\t"               // c0 *= sig(f)
        "v_fmac_f32 v61, v57, v53\n\t"              // c0 += sig(i)*tanh(g)
        "v_mul_f32 v62, v44, v62\n\t"               // c1
        "v_fmac_f32 v62, v58, v45\n\t"
        "v_mul_f32 v55, 0xC038AA3B, v61\n\t"
        "v_exp_f32 v55, v55\n\t"
        "v_mul_f32 v59, 0xC038AA3B, v62\n\t"
        "v_exp_f32 v59, v59\n\t"
        "s_nop 1\n\t"
        "v_add_f32 v55, 1.0, v55\n\t"
        "v_add_f32 v59, 1.0, v59\n\t"
        "v_rcp_f32 v55, v55\n\t"
        "v_rcp_f32 v59, v59\n\t"
        "s_nop 1\n\t"
        "v_fma_f32 v55, 2.0, v55, -1.0\n\t"         // tanh(c0)
        "v_fma_f32 v59, 2.0, v59, -1.0\n\t"         // tanh(c1)
        "v_mul_f32 v55, v54, v55\n\t"               // h0
        "v_mul_f32 v59, v46, v59\n\t"               // h1
        "ds_write_b32 v9, v55\n\t"
        "ds_write_b32 v9, v59 offset:512\n\t"
        "global_store_dword v10, v55, %[hs]\n\t"
        "global_store_dword v11, v59, %[hs]\n\t"
        "v_add_u32 v10, 0x190, v10\n\t"
        "v_add_u32 v11, 0x190, v11\n\t"
        "s_mov_b64 exec, %[onm]\n\t"
        "v_xor_b32 v8, 0x400, v8\n\t"
        "v_xor_b32 v9, 0x400, v9\n\t"
        "s_waitcnt lgkmcnt(0)\n\t"
        "s_barrier\n\t"
        "s_sub_u32 s30, s30, 1\n\t"
        "s_cmp_lg_u32 s30, 0\n\t"
        "s_cbranch_scc1 LT%=\n\t"
        "s_mov_b64 exec, s[34:35]\n\t"
        :
        : [onm] "s"(onm), [m7] "s"(m7), [wrm] "s"(wrm),
          [whh] "s"(Whh), [pre] "s"(pre), [hs] "s"(hs),
          [wo0] "v"(wo0), [wo1] "v"(wo1), [wo2] "v"(wo2), [wo3] "v"(wo3),
          [pv0] "v"(pv0), [pv1] "v"(pv1), [pvm0] "v"(pvm0), [pvm1] "v"(pvm1),
          [hs0] "v"(hs0), [hrb] "v"(hrb), [hwb] "v"(hwb),
          [mg] "v"(mg), [pk] "v"(pk), [qk] "v"(qk)
        : "memory", "scc", "s30", "s34", "s35",
          "v2","v3","v4","v5","v6","v7","v8","v9","v10","v11",
          "v12","v13","v14","v15","v16","v17","v18","v19","v20","v21",
          "v22","v23","v24","v25","v26","v27","v28","v29","v30","v31",
          "v32","v33","v34","v35","v36","v37","v38","v39","v40","v41",
          "v42","v43","v44","v45","v46","v47","v48","v49","v50","v51",
          "v52","v53","v54","v55","v56","v57","v58","v59","v60","v61","v62",
          "v64","v65","v66","v67","v68","v69","v70","v71","v72","v73",
          "v74","v75","v76","v77","v78","v79","v80","v81","v82","v83",
          "v84","v85","v86","v87","v88","v89","v90","v91","v92","v93",
          "v94","v95","v96","v97","v98","v99","v100","v101","v102","v103",
          "v104","v105","v106","v107","v108","v109","v110","v111","v112",
          "v113","v114","v115");

    __syncthreads();
    // head: final h in buf0 (t=255 read buf1, wrote buf0)
    if (do_head && tid < 128) {
        const int lane = tid & 63, wv = tid >> 6;
        float p = hbuf[0][wv * 128 + lane] * head_w[lane];
        if (lane < 36) p += hbuf[0][wv * 128 + 64 + lane] * head_w[64 + lane];
        #pragma unroll
        for (int off = 32; off; off >>= 1) p += __shfl_down(p, off);
        if (lane == 0) out[b0 + wv] = p + head_b[0];
    }
}

// ====================== x-projection GEMM (MFMA, persistent) =================
__global__ void __launch_bounds__(512, 1)
gemm_pre(const float* __restrict__ hs, const float* __restrict__ Wih,
         const float* __restrict__ bih, const float* __restrict__ bhh,
         float* __restrict__ pre)
{
    extern __shared__ short Ws[];

    const int tid = threadIdx.x;
    const int l   = tid & 63, w = tid >> 6;
    const int lr  = l & 15, lg = l >> 4;
    const int gbase = blockIdx.y * 200;

    {
        int* wz = (int*)Ws;
        for (int i = tid; i < 26624; i += 512) wz[i] = 0;
    }
    __syncthreads();

    for (int L = tid; L < 20000; L += 512) {
        const int g = L / 100, k = L % 100;
        const float v = Wih[(size_t)(gbase + g) * HH + k];
        const unsigned hh = bf16rne(v);
        const float rem = v - __uint_as_float(hh << 16);
        const unsigned lo = bf16rne(rem);
        const int kp = (((k >> 3) ^ (g & 15)) << 3) | (k & 7);
        Ws[(size_t)g * 128 + kp]          = (short)hh;
        Ws[(size_t)(208 + g) * 128 + kp]  = (short)lo;
    }
    __syncthreads();

    for (int c = 0; c < 8; ++c) {
        const int row0   = blockIdx.x * 1024 + c * 128;
        const int t      = row0 >> 9;
        const int b_base = row0 & 511;

        bf16x8 Ahi[4], Alo[4];
        {
            const float* hrow = hs + ((size_t)(b_base + 16 * w + lr) * TT + t) * HH;
            #pragma unroll
            for (int kt = 0; kt < 4; ++kt) {
                const int k0 = 32 * kt + 8 * lg;
                float4 v0 = {0.f,0.f,0.f,0.f}, v1 = {0.f,0.f,0.f,0.f};
                if (k0     <= 96) v0 = *(const float4*)(hrow + k0);
                if (k0 + 4 <= 96) v1 = *(const float4*)(hrow + k0 + 4);
                const float e[8] = {v0.x,v0.y,v0.z,v0.w,v1.x,v1.y,v1.z,v1.w};
                short sh[8], sl[8];
                #pragma unroll
                for (int i = 0; i < 8; ++i) {
                    const unsigned hh = bf16rne(e[i]);
                    const float rem = e[i] - __uint_as_float(hh << 16);
                    sh[i] = (short)hh;
                    sl[i] = (short)bf16rne(rem);
                }
                Ahi[kt] = (bf16x8){sh[0],sh[1],sh[2],sh[3],sh[4],sh[5],sh[6],sh[7]};
                Alo[kt] = (bf16x8){sl[0],sl[1],sl[2],sl[3],sl[4],sl[5],sl[6],sl[7]};
            }
        }

        #pragma unroll
        for (int n = 0; n < 13; ++n) {
            const int gp = 16 * n + lr;
            bf16x8 Bhi[4], Blo[4];
            #pragma unroll
            for (int kt = 0; kt < 4; ++kt) {
                const int slot = (4 * kt + lg) ^ (gp & 15);
                Bhi[kt] = *(const bf16x8*)&Ws[(size_t)gp * 128 + slot * 8];
                Blo[kt] = *(const bf16x8*)&Ws[(size_t)(208 + gp) * 128 + slot * 8];
            }
            f32x4 acc = {0.f, 0.f, 0.f, 0.f};
            #pragma unroll
            for (int kt = 0; kt < 4; ++kt) {
                acc = __builtin_amdgcn_mfma_f32_16x16x32_bf16(Ahi[kt], Bhi[kt], acc, 0, 0, 0);
                acc = __builtin_amdgcn_mfma_f32_16x16x32_bf16(Alo[kt], Bhi[kt], acc, 0, 0, 0);
                acc = __builtin_amdgcn_mfma_f32_16x16x32_bf16(Ahi[kt], Blo[kt], acc, 0, 0, 0);
            }
            if (gp < 200) {
                const int gcol = gbase + gp;
                const float bsum = bih[gcol] + bhh[gcol];
                #pragma unroll
                for (int r = 0; r < 4; ++r) {
                    const size_t row = (size_t)row0 + 16 * w + 4 * lg + r;
                    pre[row * GG + gcol] = acc[r] + bsum;
                }
            }
        }
    }
}

// =============================================================================
extern "C" void kernel_launch(void* const* d_in, const int* in_sizes, int n_in,
                              void* d_out, int out_size, void* d_ws, size_t ws_size,
                              hipStream_t stream) {
    const float* x         = (const float*)d_in[0];
    const float* W_ih0     = (const float*)d_in[1];
    const float* W_ih_rest = (const float*)d_in[2];
    const float* W_hh      = (const float*)d_in[3];
    const float* b_ih      = (const float*)d_in[4];
    const float* b_hh      = (const float*)d_in[5];
    const float* head_w    = (const float*)d_in[6];
    const float* head_b    = (const float*)d_in[7];
    float* out = (float*)d_out;

    const size_t HS_BYTES = (size_t)BB * TT * HH * 4;
    float* hs  = (float*)d_ws;
    float* pre = (float*)((char*)d_ws + HS_BYTES);

    const int gemm_lds = 2 * 208 * 128 * 2;
    hipFuncSetAttribute((const void*)gemm_pre,
                        hipFuncAttributeMaxDynamicSharedMemorySize, gemm_lds);
    dim3 ggrid(128, 2);

    lstm_recur<0><<<512, 448, 0, stream>>>(
        x, nullptr, W_hh, W_ih0, b_ih, b_hh, head_w, head_b, hs, out);

    gemm_pre<<<ggrid, 512, gemm_lds, stream>>>(hs, W_ih_rest, b_ih + GG, b_hh + GG, pre);
    lstm_recur_asm<<<256, 1024, 0, stream>>>(
        pre, W_hh + 40000, head_w, head_b, hs, out, 0);

    gemm_pre<<<ggrid, 512, gemm_lds, stream>>>(hs, W_ih_rest + 40000, b_ih + 2*GG, b_hh + 2*GG, pre);
    lstm_recur_asm<<<256, 1024, 0, stream>>>(
        pre, W_hh + 80000, head_w, head_b, hs, out, 1);
}